// Round 8
// baseline (369.373 us; speedup 1.0000x reference)
//
#include <hip/hip_runtime.h>

// AssociativeScanGateLoop: h_t = f_t*h_{t-1} + i_t*v_t per (b,d) sequence.
// x: (B=4, T=8192, 3*512) fp32.  out: (4, 8192, 512) fp32.
//
// v3: latency-bound fix. Round-6 profile showed all 3 kernels < 119 us each,
// ~328 total => ~1.1 TB/s effective = classic under-occupancy latency bound
// (2 waves/SIMD, ~1 load in flight). Changes:
//   - C 256 -> 512 (2048 blocks, 4 waves/SIMD for K1/K2)
//   - explicit depth-2 register prefetch pipeline in K1/K2
//   - KS: 512 threads (1 channel/thread, coalesced) + depth-1 prefetch

#define B_  4
#define T_  8192
#define DH_ 512
#define ROW_ 1536

// clang ext-vector: __builtin_nontemporal_store requires this, not HIP float4.
typedef float f32x4 __attribute__((ext_vector_type(4)));

__device__ __forceinline__ float rcp_f(float x) {
    return __builtin_amdgcn_rcpf(x);   // v_rcp_f32 — avoids div expansion
}
__device__ __forceinline__ float sigmoid_f(float x) {
    return rcp_f(1.0f + __expf(-x));
}
__device__ __forceinline__ float tanh_f(float x) {
    // 1 - 2/(e^{2x}+1): saturates to +/-1 even when __expf overflows to inf.
    return 1.0f - 2.0f * rcp_f(__expf(2.0f * x) + 1.0f);
}

// K1: per-chunk affine aggregate (A, KV). One chunk per block, 128 threads,
// 4 consecutive channels per thread. Depth-2 software pipeline: rows i+2
// load while row i computes, so each wave keeps >=2 wave-loads in flight.
__global__ void k_partials(const float* __restrict__ x,
                           float* __restrict__ agg_a,
                           float* __restrict__ agg_kv,
                           int C, int Tc) {
    const int c = blockIdx.x;
    const int b = blockIdx.y;
    const int d = threadIdx.x << 2;                      // channel base
    const float* xb = x + ((size_t)b * T_ + (size_t)c * Tc) * ROW_;

    float A[4]  = {1.f, 1.f, 1.f, 1.f};
    float KV[4] = {0.f, 0.f, 0.f, 0.f};

    // prologue: rows 0 and 1 (Tc >= 16 always on the chunked path)
    f32x4 x0 = *(const f32x4*)(xb + d);
    f32x4 g0 = *(const f32x4*)(xb + DH_ + d);
    const float* r1 = xb + ROW_;
    f32x4 x1 = *(const f32x4*)(r1 + d);
    f32x4 g1 = *(const f32x4*)(r1 + DH_ + d);

#pragma unroll 4
    for (int i = 0; i < Tc; ++i) {
        const int ip = (i + 2 < Tc) ? (i + 2) : (Tc - 1);   // clamped prefetch
        const float* rp = xb + (size_t)ip * ROW_;
        const f32x4 xn = *(const f32x4*)(rp + d);
        const f32x4 gn = *(const f32x4*)(rp + DH_ + d);
#pragma unroll
        for (int j = 0; j < 4; ++j) {
            const float s  = sigmoid_f(g0[j]);
            const float f  = 1.0f - s;
            const float iv = tanh_f(x0[j]) * s;
            A[j]  = f * A[j];
            KV[j] = fmaf(f, KV[j], iv);
        }
        x0 = x1; g0 = g1;   // rotate pipeline (SSA renames, no scratch)
        x1 = xn; g1 = gn;
    }
    const size_t idx = ((size_t)b * C + c) * DH_ + d;
    f32x4 Av  = {A[0],  A[1],  A[2],  A[3]};
    f32x4 KVv = {KV[0], KV[1], KV[2], KV[3]};
    *(f32x4*)(agg_a + idx)  = Av;
    *(f32x4*)(agg_kv + idx) = KVv;
}

// KS: exclusive scan over chunk aggregates. One channel per thread (512
// threads, fully coalesced 4B loads/stores across the block), depth-1
// prefetch so the serial fma chain pipelines the loads.
__global__ void k_scan(const float* __restrict__ agg_a,
                       const float* __restrict__ agg_kv,
                       float* __restrict__ h0,
                       int C) {
    const int b = blockIdx.x;
    const int d = threadIdx.x;                            // one channel
    const size_t base = (size_t)b * C * DH_ + d;

    float h  = 0.f;
    float ac = agg_a[base];
    float kc = agg_kv[base];
#pragma unroll 4
    for (int c = 0; c < C; ++c) {
        const int cp = (c + 1 < C) ? (c + 1) : c;         // clamped prefetch
        const float an = agg_a[base + (size_t)cp * DH_];
        const float kn = agg_kv[base + (size_t)cp * DH_];
        h0[base + (size_t)c * DH_] = h;                   // exclusive prefix
        h = fmaf(ac, h, kc);
        ac = an; kc = kn;
    }
}

// K2: seed from h0, recompute chunk, write gated output. Same depth-2
// pipeline over three streams (xi, gi, go).
__global__ void k_apply(const float* __restrict__ x,
                        const float* __restrict__ h0buf,
                        float* __restrict__ out,
                        int C, int Tc) {
    const int c = blockIdx.x;
    const int b = blockIdx.y;
    const int d = threadIdx.x << 2;

    float h[4] = {0.f, 0.f, 0.f, 0.f};
    if (h0buf) {
        const f32x4 hv = *(const f32x4*)(h0buf + ((size_t)b * C + c) * DH_ + d);
#pragma unroll
        for (int j = 0; j < 4; ++j) h[j] = hv[j];
    }

    const float* xb = x + ((size_t)b * T_ + (size_t)c * Tc) * ROW_;
    float* ob = out + ((size_t)b * T_ + (size_t)c * Tc) * DH_;

    f32x4 x0 = *(const f32x4*)(xb + d);
    f32x4 g0 = *(const f32x4*)(xb + DH_ + d);
    f32x4 o0 = *(const f32x4*)(xb + 2 * DH_ + d);
    const float* r1 = xb + ROW_;
    f32x4 x1 = *(const f32x4*)(r1 + d);
    f32x4 g1 = *(const f32x4*)(r1 + DH_ + d);
    f32x4 o1 = *(const f32x4*)(r1 + 2 * DH_ + d);

#pragma unroll 4
    for (int i = 0; i < Tc; ++i) {
        const int ip = (i + 2 < Tc) ? (i + 2) : (Tc - 1);
        const float* rp = xb + (size_t)ip * ROW_;
        const f32x4 xn = *(const f32x4*)(rp + d);
        const f32x4 gn = *(const f32x4*)(rp + DH_ + d);
        const f32x4 on = *(const f32x4*)(rp + 2 * DH_ + d);

        f32x4 o;
#pragma unroll
        for (int j = 0; j < 4; ++j) {
            const float s  = sigmoid_f(g0[j]);
            const float f  = 1.0f - s;
            const float iv = tanh_f(x0[j]) * s;
            h[j] = fmaf(f, h[j], iv);
            o[j] = tanh_f(h[j]) * sigmoid_f(o0[j]);
        }
        // out is never re-read: nontemporal store leaves L3 to x.
        __builtin_nontemporal_store(o, (f32x4*)(ob + (size_t)i * DH_ + d));

        x0 = x1; g0 = g1; o0 = o1;
        x1 = xn; g1 = gn; o1 = on;
    }
}

extern "C" void kernel_launch(void* const* d_in, const int* in_sizes, int n_in,
                              void* d_out, int out_size, void* d_ws, size_t ws_size,
                              hipStream_t stream) {
    const float* x = (const float*)d_in[0];
    float* out = (float*)d_out;

    // Pick chunk count C (power of two dividing T) so 3 aggregate arrays fit ws.
    int C = 512;               // Tc = 16; needs 12 MiB ws (measured ws ~768 MiB)
    while (C > 1 && (size_t)B_ * C * DH_ * 3 * sizeof(float) > ws_size) C >>= 1;

    const dim3 blk(DH_ / 4);   // 128 threads, 4 channels each

    if (C == 1) {
        // No usable workspace: single sequential pass per channel (slow, correct).
        hipLaunchKernelGGL(k_apply, dim3(1, B_), blk, 0, stream,
                           x, (const float*)nullptr, out, 1, T_);
        return;
    }

    const int Tc = T_ / C;
    float* agg_a  = (float*)d_ws;
    float* agg_kv = agg_a  + (size_t)B_ * C * DH_;
    float* h0     = agg_kv + (size_t)B_ * C * DH_;

    const dim3 grid(C, B_);
    hipLaunchKernelGGL(k_partials, grid, blk, 0, stream, x, agg_a, agg_kv, C, Tc);
    hipLaunchKernelGGL(k_scan, dim3(B_), dim3(DH_), 0, stream, agg_a, agg_kv, h0, C);
    hipLaunchKernelGGL(k_apply, grid, blk, 0, stream, x, h0, out, C, Tc);
}

// Round 10
// 316.212 us; speedup vs baseline: 1.1681x; 1.1681x over previous
//
#include <hip/hip_runtime.h>

// AssociativeScanGateLoop: h_t = f_t*h_{t-1} + i_t*v_t per (b,d) sequence.
// x: (B=4, T=8192, 3*512) fp32.  out: (4, 8192, 512) fp32.
//
// v4: revert to v2.2 config (C=256, plain K1/K2 bodies — measured best at
// 328.6 us) and fix the serial-scan kernel: v2.2's KS ran 4 blocks (4 CUs!)
// with a ~450cyc/iter dependent chain over C iterations (~45 us). Now KS is
// a Kogge-Stone scan over affine maps: one block per (b,d) channel
// (2048 blocks), C threads each, 8 LDS steps. Expected ~4 us.

#define B_  4
#define T_  8192
#define DH_ 512
#define ROW_ 1536

// clang ext-vector: __builtin_nontemporal_store requires this, not HIP float4.
typedef float f32x4 __attribute__((ext_vector_type(4)));

__device__ __forceinline__ float rcp_f(float x) {
    return __builtin_amdgcn_rcpf(x);   // v_rcp_f32 — avoids div expansion
}
__device__ __forceinline__ float sigmoid_f(float x) {
    return rcp_f(1.0f + __expf(-x));
}
__device__ __forceinline__ float tanh_f(float x) {
    // 1 - 2/(e^{2x}+1): saturates to +/-1 even when __expf overflows to inf.
    return 1.0f - 2.0f * rcp_f(__expf(2.0f * x) + 1.0f);
}

// K1: per-chunk affine aggregate (A, KV). One chunk per block, 128 threads,
// 4 consecutive channels per thread (16B coalesced loads). v2.2 body.
__global__ void k_partials(const float* __restrict__ x,
                           float* __restrict__ agg_a,
                           float* __restrict__ agg_kv,
                           int C, int Tc) {
    const int c = blockIdx.x;
    const int b = blockIdx.y;
    const int d = threadIdx.x << 2;                      // channel base
    const float* xb = x + ((size_t)b * T_ + (size_t)c * Tc) * ROW_;

    float A[4]  = {1.f, 1.f, 1.f, 1.f};
    float KV[4] = {0.f, 0.f, 0.f, 0.f};
#pragma unroll 8
    for (int i = 0; i < Tc; ++i) {
        const float* r = xb + (size_t)i * ROW_;
        const f32x4 xi = *(const f32x4*)(r + d);
        const f32x4 gi = *(const f32x4*)(r + DH_ + d);
#pragma unroll
        for (int j = 0; j < 4; ++j) {
            const float s  = sigmoid_f(gi[j]);
            const float f  = 1.0f - s;
            const float iv = tanh_f(xi[j]) * s;
            A[j]  = f * A[j];
            KV[j] = fmaf(f, KV[j], iv);
        }
    }
    const size_t idx = ((size_t)b * C + c) * DH_ + d;
    f32x4 Av  = {A[0],  A[1],  A[2],  A[3]};
    f32x4 KVv = {KV[0], KV[1], KV[2], KV[3]};
    *(f32x4*)(agg_a + idx)  = Av;
    *(f32x4*)(agg_kv + idx) = KVv;
}

// KS: Kogge-Stone inclusive scan of affine maps (a,kv) over the C chunks,
// one block per (b,d) channel, C threads (thread c owns chunk c).
// h0[c] = kv-part of inclusive composite over chunks [0..c-1] (h_init = 0).
// Loads are strided (stride DH_) but total volume is only 4 MiB, fresh in
// cache from K1. 2*log2(C) barriers.
__global__ void k_scan(const float* __restrict__ agg_a,
                       const float* __restrict__ agg_kv,
                       float* __restrict__ h0,
                       int C) {
    __shared__ float sa[1024];
    __shared__ float sk[1024];
    const int d = blockIdx.x;             // channel
    const int b = blockIdx.y;
    const int c = threadIdx.x;            // chunk index

    const size_t idx = ((size_t)b * C + c) * DH_ + d;
    float am = agg_a[idx];
    float km = agg_kv[idx];
    sa[c] = am;
    sk[c] = km;
    __syncthreads();

    for (int o = 1; o < C; o <<= 1) {
        float ap = 1.f, kp = 0.f;
        if (c >= o) { ap = sa[c - o]; kp = sk[c - o]; }
        __syncthreads();                  // all reads before any writes
        km = fmaf(am, kp, km);            // compose: own ∘ prev (uses old am)
        am = am * ap;
        sa[c] = am;
        sk[c] = km;
        __syncthreads();
    }

    const float h = (c == 0) ? 0.f : sk[c - 1];
    h0[idx] = h;
}

// K2: seed from h0, recompute chunk, write gated output. v2.2 body.
__global__ void k_apply(const float* __restrict__ x,
                        const float* __restrict__ h0buf,
                        float* __restrict__ out,
                        int C, int Tc) {
    const int c = blockIdx.x;
    const int b = blockIdx.y;
    const int d = threadIdx.x << 2;

    float h[4] = {0.f, 0.f, 0.f, 0.f};
    if (h0buf) {
        const f32x4 hv = *(const f32x4*)(h0buf + ((size_t)b * C + c) * DH_ + d);
#pragma unroll
        for (int j = 0; j < 4; ++j) h[j] = hv[j];
    }

    const float* xb = x + ((size_t)b * T_ + (size_t)c * Tc) * ROW_;
    float* ob = out + ((size_t)b * T_ + (size_t)c * Tc) * DH_;

#pragma unroll 4
    for (int i = 0; i < Tc; ++i) {
        const float* r = xb + (size_t)i * ROW_;
        const f32x4 xi = *(const f32x4*)(r + d);
        const f32x4 gi = *(const f32x4*)(r + DH_ + d);
        const f32x4 go = *(const f32x4*)(r + 2 * DH_ + d);
        f32x4 o;
#pragma unroll
        for (int j = 0; j < 4; ++j) {
            const float s  = sigmoid_f(gi[j]);
            const float f  = 1.0f - s;
            const float iv = tanh_f(xi[j]) * s;
            h[j] = fmaf(f, h[j], iv);
            o[j] = tanh_f(h[j]) * sigmoid_f(go[j]);
        }
        // out is never re-read: nontemporal store leaves L3 to x.
        __builtin_nontemporal_store(o, (f32x4*)(ob + (size_t)i * DH_ + d));
    }
}

extern "C" void kernel_launch(void* const* d_in, const int* in_sizes, int n_in,
                              void* d_out, int out_size, void* d_ws, size_t ws_size,
                              hipStream_t stream) {
    const float* x = (const float*)d_in[0];
    float* out = (float*)d_out;

    const dim3 blk(DH_ / 4);   // 128 threads, 4 channels each

    // Pick chunk count C (power of two dividing T) so 3 aggregate arrays fit ws.
    int C = 256;               // Tc = 32; needs 6 MiB ws (measured ws ~768 MiB)
    while (C > 1 && (size_t)B_ * C * DH_ * 3 * sizeof(float) > ws_size) C >>= 1;

    if (C == 1) {
        // No usable workspace: single sequential pass per channel (slow, correct).
        hipLaunchKernelGGL(k_apply, dim3(1, B_), blk, 0, stream,
                           x, (const float*)nullptr, out, 1, T_);
        return;
    }

    const int Tc = T_ / C;
    float* agg_a  = (float*)d_ws;
    float* agg_kv = agg_a  + (size_t)B_ * C * DH_;
    float* h0     = agg_kv + (size_t)B_ * C * DH_;

    const dim3 grid(C, B_);
    hipLaunchKernelGGL(k_partials, grid, blk, 0, stream, x, agg_a, agg_kv, C, Tc);
    // KS: one block per (b,d) channel, C threads each (C <= 256 here).
    hipLaunchKernelGGL(k_scan, dim3(DH_, B_), dim3(C), 0, stream,
                       agg_a, agg_kv, h0, C);
    hipLaunchKernelGGL(k_apply, grid, blk, 0, stream, x, h0, out, C, Tc);
}